// Round 2
// baseline (3993.375 us; speedup 1.0000x reference)
//
#include <hip/hip_runtime.h>
#include <hip/hip_bf16.h>
#include <math.h>

typedef __hip_bfloat16 bf16;

// Problem constants (fixed by reference)
#define B_      8
#define S_      2048
#define DIN     1024
#define DSTATE  1024
#define H_      16
#define DH_     64
#define PROJ4   4096   // 4*DSTATE

// ---------------------------------------------------------------------------
// bf16 <-> f32 helpers (bit-level, RNE for store)
// ---------------------------------------------------------------------------
__device__ __forceinline__ unsigned short f2bf(float f) {
    unsigned int x = __float_as_uint(f);
    x += 0x7FFFu + ((x >> 16) & 1u);   // round-to-nearest-even
    return (unsigned short)(x >> 16);
}
__device__ __forceinline__ float bf2f(unsigned short u) {
    return __uint_as_float(((unsigned int)u) << 16);
}

// 4-element vector load/store, overloaded on element type
__device__ __forceinline__ float4 load4(const float* p) { return *(const float4*)p; }
__device__ __forceinline__ float4 load4(const bf16* p) {
    uint2 u = *(const uint2*)p;    // 4 bf16 = 8 bytes
    float4 r;
    r.x = __uint_as_float((u.x & 0xFFFFu) << 16);
    r.y = __uint_as_float(u.x & 0xFFFF0000u);
    r.z = __uint_as_float((u.y & 0xFFFFu) << 16);
    r.w = __uint_as_float(u.y & 0xFFFF0000u);
    return r;
}
__device__ __forceinline__ void store4(float* p, float4 v) { *(float4*)p = v; }
__device__ __forceinline__ void store4(bf16* p, float4 v) {
    uint2 u;
    u.x = (unsigned int)f2bf(v.x) | ((unsigned int)f2bf(v.y) << 16);
    u.y = (unsigned int)f2bf(v.z) | ((unsigned int)f2bf(v.w) << 16);
    *(uint2*)p = u;
}

// ---------------------------------------------------------------------------
// GEMM: C[M,N] = A[M,K] @ B[K,N]; A has row stride lda (elements), B,C dense.
// fp32 accumulate; A may be fp32 or bf16, C may be fp32 or bf16.
// 128x128 tile, BK=8, 256 threads, 8x8 micro-tile split 4+4 (2-way LDS
// aliasing only, which is free on gfx950).
// ---------------------------------------------------------------------------
template <typename TA, typename TC>
__global__ __launch_bounds__(256) void gemm128(const TA* __restrict__ A,
                                               const float* __restrict__ Bm,
                                               TC* __restrict__ C,
                                               int M, int N, int K, int lda) {
    __shared__ float As[8][128];   // As[k][m]
    __shared__ float Bs[8][128];   // Bs[k][n]

    const int tid = threadIdx.x;
    const int tx = tid & 15;
    const int ty = tid >> 4;
    const int m0 = blockIdx.y * 128;
    const int n0 = blockIdx.x * 128;

    const int aRow = tid >> 1;        // 0..127
    const int aCol = (tid & 1) * 4;   // 0 or 4
    const int bRow = tid >> 5;        // 0..7
    const int bCol = (tid & 31) * 4;  // 0..124

    const TA* Aptr = A + (size_t)(m0 + aRow) * lda + aCol;
    const float* Bptr = Bm + (size_t)bRow * N + n0 + bCol;

    float acc[8][8];
    #pragma unroll
    for (int i = 0; i < 8; ++i)
        #pragma unroll
        for (int j = 0; j < 8; ++j) acc[i][j] = 0.0f;

    for (int k0 = 0; k0 < K; k0 += 8) {
        float4 av = load4(Aptr + k0);
        float4 bv = load4(Bptr + (size_t)k0 * N);
        __syncthreads();
        As[aCol + 0][aRow] = av.x;
        As[aCol + 1][aRow] = av.y;
        As[aCol + 2][aRow] = av.z;
        As[aCol + 3][aRow] = av.w;
        *(float4*)&Bs[bRow][bCol] = bv;
        __syncthreads();

        #pragma unroll
        for (int kk = 0; kk < 8; ++kk) {
            float4 a0 = *(const float4*)&As[kk][ty * 4];
            float4 a1 = *(const float4*)&As[kk][64 + ty * 4];
            float4 b0 = *(const float4*)&Bs[kk][tx * 4];
            float4 b1 = *(const float4*)&Bs[kk][64 + tx * 4];
            float a[8] = {a0.x, a0.y, a0.z, a0.w, a1.x, a1.y, a1.z, a1.w};
            float b[8] = {b0.x, b0.y, b0.z, b0.w, b1.x, b1.y, b1.z, b1.w};
            #pragma unroll
            for (int i = 0; i < 8; ++i)
                #pragma unroll
                for (int j = 0; j < 8; ++j)
                    acc[i][j] = fmaf(a[i], b[j], acc[i][j]);
        }
    }

    #pragma unroll
    for (int i = 0; i < 8; ++i) {
        int m = (i < 4) ? (ty * 4 + i) : (64 + ty * 4 + (i - 4));
        TC* cp = C + (size_t)(m0 + m) * N + n0;
        float4 v0 = {acc[i][0], acc[i][1], acc[i][2], acc[i][3]};
        float4 v1 = {acc[i][4], acc[i][5], acc[i][6], acc[i][7]};
        store4(cp + tx * 4, v0);
        store4(cp + 64 + tx * 4, v1);
    }
}

// ---------------------------------------------------------------------------
// Recurrence: one wave64 per (b,h) chain; lane e owns output element e.
// Weights in VGPRs (lane e holds column e of Wc/Wf/Wr); h broadcast via
// readlane. h_t is written IN PLACE over the consumed xi slot (lane-private
// address; the t+1 prefetch precedes the t write, so no hazard).
// ---------------------------------------------------------------------------
__device__ __forceinline__ float lane_bcast(float v, int lane) {
    return __int_as_float(__builtin_amdgcn_readlane(__float_as_int(v), lane));
}

__global__ __launch_bounds__(64, 1) void recur_kernel(bf16* __restrict__ proj,
                                                      const float* __restrict__ sw) {
    const int e = threadIdx.x;     // 0..63
    const int bh = blockIdx.x;     // 0..127
    const int b = bh >> 4;
    const int h = bh & 15;

    const float* Wc_p = sw + (size_t)h * DH_ * DH_;
    const float* Wf_p = sw + (size_t)(H_ + h) * DH_ * DH_;
    const float* Wr_p = sw + (size_t)(2 * H_ + h) * DH_ * DH_;

    float Wc[64], Wf[64], Wr[64];
    #pragma unroll
    for (int d = 0; d < 64; ++d) {
        Wc[d] = Wc_p[d * 64 + e];
        Wf[d] = Wf_p[d * 64 + e];
        Wr[d] = Wr_p[d * 64 + e];
    }

    bf16* xi_p = proj + (size_t)b * S_ * PROJ4 + h * 64 + e;   // cols [0:1024)
    const bf16* xf_p = xi_p + 1024;                            // [1024:2048)
    const bf16* xr_p = xi_p + 2048;                            // [2048:3072)

    float hreg = 0.0f;
    float xiv = __bfloat162float(xi_p[0]);
    float xfv = __bfloat162float(xf_p[0]);
    float xrv = __bfloat162float(xr_p[0]);

    for (int t = 0; t < S_; ++t) {
        float xin = 0.f, xfn = 0.f, xrn = 0.f;
        if (t + 1 < S_) {
            size_t o = (size_t)(t + 1) * PROJ4;
            xin = __bfloat162float(xi_p[o]);
            xfn = __bfloat162float(xf_p[o]);
            xrn = __bfloat162float(xr_p[o]);
        }

        float ar0 = xrv, ar1 = 0.f, af0 = xfv, af1 = 0.f;
        #pragma unroll
        for (int d = 0; d < 64; d += 2) {
            float hv0 = lane_bcast(hreg, d);
            float hv1 = lane_bcast(hreg, d + 1);
            ar0 = fmaf(hv0, Wr[d],     ar0);
            ar1 = fmaf(hv1, Wr[d + 1], ar1);
            af0 = fmaf(hv0, Wf[d],     af0);
            af1 = fmaf(hv1, Wf[d + 1], af1);
        }
        float r = 1.f / (1.f + __expf(-(ar0 + ar1)));
        float f = 1.f / (1.f + __expf(-(af0 + af1)));

        float rh = r * hreg;
        float ac0 = xiv, ac1 = 0.f;
        #pragma unroll
        for (int d = 0; d < 64; d += 2) {
            ac0 = fmaf(lane_bcast(rh, d),     Wc[d],     ac0);
            ac1 = fmaf(lane_bcast(rh, d + 1), Wc[d + 1], ac1);
        }
        float a = ac0 + ac1;
        a = fminf(fmaxf(a, -15.f), 15.f);
        float ex = __expf(-2.f * a);
        float c = (1.f - ex) / (1.f + ex);    // tanh

        hreg = f * hreg + (1.f - f) * c;
        xi_p[(size_t)t * PROJ4] = __float2bfloat16(hreg);   // h_t over xi slot

        xiv = xin; xfv = xfn; xrv = xrn;
    }
}

// ---------------------------------------------------------------------------
// Gated RMSNorm in place: y = rmsnorm(h * silu(g)) * nw over proj cols [0:1024).
// One 256-thread block per row, 4 elements/thread.
// ---------------------------------------------------------------------------
__global__ __launch_bounds__(256) void gate_norm_kernel(bf16* __restrict__ proj,
                                                        const float* __restrict__ nw) {
    const int row = blockIdx.x;        // 0 .. B*S-1
    const int tid = threadIdx.x;
    __shared__ float red[4];

    bf16* hp = proj + (size_t)row * PROJ4;        // h in cols [0:1024)
    const bf16* gp = hp + 3 * DSTATE;             // g in cols [3072:4096)

    float4 hv = load4(hp + tid * 4);
    float4 gv = load4(gp + tid * 4);

    float v0 = hv.x * (gv.x / (1.f + __expf(-gv.x)));
    float v1 = hv.y * (gv.y / (1.f + __expf(-gv.y)));
    float v2 = hv.z * (gv.z / (1.f + __expf(-gv.z)));
    float v3 = hv.w * (gv.w / (1.f + __expf(-gv.w)));

    float ss = v0 * v0 + v1 * v1 + v2 * v2 + v3 * v3;
    #pragma unroll
    for (int mask = 32; mask >= 1; mask >>= 1)
        ss += __shfl_xor(ss, mask, 64);

    const int wid = tid >> 6;
    if ((tid & 63) == 0) red[wid] = ss;
    __syncthreads();
    float tot = red[0] + red[1] + red[2] + red[3];
    float scale = rsqrtf(tot * (1.0f / (float)DSTATE) + 1e-6f);

    float4 nv = *(const float4*)(nw + tid * 4);
    float4 y;
    y.x = v0 * scale * nv.x;
    y.y = v1 * scale * nv.y;
    y.z = v2 * scale * nv.z;
    y.w = v3 * scale * nv.w;
    store4(hp + tid * 4, y);
}

// ---------------------------------------------------------------------------
extern "C" void kernel_launch(void* const* d_in, const int* in_sizes, int n_in,
                              void* d_out, int out_size, void* d_ws, size_t ws_size,
                              hipStream_t stream) {
    const float* x     = (const float*)d_in[0];   // [B,S,DIN]
    const float* w_in  = (const float*)d_in[1];   // [DIN, 4*DSTATE]
    const float* sw    = (const float*)d_in[2];   // [3H, DH, DH]
    const float* nw    = (const float*)d_in[3];   // [DSTATE]
    const float* w_out = (const float*)d_in[4];   // [DSTATE, DOUT]
    float* out = (float*)d_out;

    bf16* proj = (bf16*)d_ws;    // [B*S, 4096] bf16 = 134 MB (only ws use)

    // 1) input projection GEMM: [16384,1024]f32 @ [1024,4096]f32 -> bf16
    dim3 g1(PROJ4 / 128, (B_ * S_) / 128);
    gemm128<float, bf16><<<g1, 256, 0, stream>>>(x, w_in, proj,
                                                 B_ * S_, PROJ4, DIN, DIN);

    // 2) sequential gated recurrence: h_t overwrites xi slot (cols 0:1024)
    recur_kernel<<<128, 64, 0, stream>>>(proj, sw);

    // 3) gate + rmsnorm in place over cols 0:1024
    gate_norm_kernel<<<B_ * S_, 256, 0, stream>>>(proj, nw);

    // 4) output projection GEMM: y(bf16, lda=4096) @ [1024,1024]f32 -> f32 out
    dim3 g2(DSTATE / 128, (B_ * S_) / 128);
    gemm128<bf16, float><<<g2, 256, 0, stream>>>(proj, w_out, out,
                                                 B_ * S_, DSTATE, DSTATE, PROJ4);
}